// Round 9
// baseline (265.978 us; speedup 1.0000x reference)
//
#include <hip/hip_runtime.h>

#define BB 4
#define CC 256
#define HH 48
#define WW 48
#define HWHW 2304
#define KK 49
#define RELN 128

// ws layout (floats): q | k | v | sbuf | WT
// q,k,v channel-packed: [b][c/4][h][w][4]
#define QSZ (BB*CC*HWHW)            // 2359296 floats per tensor
#define ATTNOFF (3*QSZ)             // sbuf: [B][H][64][W] (taps 0-48, qx 49-55, qy 56-62)
#define SBUF_FLOATS (BB*HH*64*WW)   // 589824
#define WTOFF (ATTNOFF + SBUF_FLOATS)
// XT (bf16 hi/lo of x, PRE-SWIZZLED chunks) lives in d_out

typedef short bf16x8 __attribute__((ext_vector_type(8)));
typedef float f32x4 __attribute__((ext_vector_type(4)));

__device__ __forceinline__ void split_bf16(float f, unsigned short& hi, unsigned short& lo)
{
    unsigned u = __float_as_uint(f);
    hi = (unsigned short)(u >> 16);
    float r = f - __uint_as_float(u & 0xFFFF0000u);
    unsigned v = __float_as_uint(r);
    v += 0x7FFFu + ((v >> 16) & 1u);
    lo = (unsigned short)(v >> 16);
}

__device__ __forceinline__ void gload16(const uint4* g, uint4* l)
{
    __builtin_amdgcn_global_load_lds(
        (const __attribute__((address_space(1))) void*)g,
        (__attribute__((address_space(3))) void*)l, 16, 0, 0);
}

// ---------------- prep: zero sbuf | convert x -> XT | convert w -> WT ----------------
__global__ __launch_bounds__(256) void prep_kernel(
    const float* __restrict__ x,
    const float* __restrict__ wq, const float* __restrict__ wk,
    const float* __restrict__ wvp,
    unsigned short* __restrict__ xt, unsigned short* __restrict__ wt,
    float* __restrict__ ws)
{
    __shared__ unsigned short lds[32*520];
    const int bid = blockIdx.x;
    const int t = threadIdx.x;

    if (bid < 576) {                       // zero sbuf
        float4* p = (float4*)(ws + ATTNOFF);
        p[bid*256 + t] = make_float4(0.f,0.f,0.f,0.f);
        return;
    }
    if (bid < 864) {                       // convert_x, 288 blocks
        const int bid2 = bid - 576;
        const int b = bid2 / 72;
        const int hw0 = (bid2 % 72) * 32;
        const int hw = t & 31, cp = t >> 5;
        #pragma unroll 4
        for (int i = 0; i < 32; ++i) {
            int c = i*8 + cp;
            float f = x[((size_t)b*CC + c)*HWHW + hw0 + hw];
            unsigned short hi, lo; split_bf16(f, hi, lo);
            int ch = i*2;
            lds[hw*520 + ((ch       ^ (hw&7))*8) + cp] = hi;
            lds[hw*520 + (((ch + 1) ^ (hw&7))*8) + cp] = lo;
        }
        __syncthreads();
        const int hw2 = t >> 3, u = t & 7;
        uint4* xt4 = (uint4*)xt;
        const size_t rowbase = ((size_t)b*HWHW + hw0 + hw2) * 64;
        #pragma unroll
        for (int j = 0; j < 8; ++j) {
            int chunk = j*8 + u;
            uint4 v = *(const uint4*)&lds[hw2*520 + chunk*8];
            xt4[rowbase + chunk] = v;
        }
        return;
    }
    {                                       // convert_w, 96 blocks
        const int tt = (bid - 864)*256 + t;
        const int m = tt >> 5, kg = tt & 31;
        const float* src = (m < 256) ? wq : (m < 512) ? wk : wvp;
        const float* row = src + (size_t)(m & 255)*256 + kg*8;
        unsigned short h[8], l[8];
        #pragma unroll
        for (int j = 0; j < 8; ++j) split_bf16(row[j], h[j], l[j]);
        uint4 hv, lv;
        hv.x = (unsigned)h[0] | ((unsigned)h[1]<<16); hv.y = (unsigned)h[2] | ((unsigned)h[3]<<16);
        hv.z = (unsigned)h[4] | ((unsigned)h[5]<<16); hv.w = (unsigned)h[6] | ((unsigned)h[7]<<16);
        lv.x = (unsigned)l[0] | ((unsigned)l[1]<<16); lv.y = (unsigned)l[2] | ((unsigned)l[3]<<16);
        lv.z = (unsigned)l[4] | ((unsigned)l[5]<<16); lv.w = (unsigned)l[6] | ((unsigned)l[7]<<16);
        uint4* dstrow = (uint4*)wt + (size_t)m*64;
        const int ks = kg >> 2, s_hi = 2*(kg & 3);
        dstrow[ks*8 + ( s_hi      ^ (m&7))] = hv;
        dstrow[ks*8 + ((s_hi + 1) ^ (m&7))] = lv;
    }
}

// ---------------- Projection GEMM (unchanged from R8) ----------------
__global__ __launch_bounds__(256) void proj_gemm_kernel(
    const unsigned short* __restrict__ xt,
    const unsigned short* __restrict__ wt,
    float* __restrict__ ws)
{
    __shared__ uint4 smem[2][1536];
    const int n0 = blockIdx.x * 128;
    const int m0 = blockIdx.y * 64;
    const int b = n0 / HWHW;
    const int hwb = n0 % HWHW;
    const int tid = threadIdx.x;
    const int wid = tid >> 6, ln = tid & 63;
    const int wm = wid >> 1, wn = wid & 1;
    const int l15 = ln & 15, g = ln >> 4;

    f32x4 acc[2][4];
    #pragma unroll
    for (int i = 0; i < 2; ++i)
        #pragma unroll
        for (int j = 0; j < 4; ++j) acc[i][j] = (f32x4){0.f,0.f,0.f,0.f};

    const uint4* wt4 = (const uint4*)wt;
    const uint4* xt4 = (const uint4*)xt;
    const int lrow = ln >> 3, lslot = ln & 7;

    #define STAGE(bf, ks)                                                          \
        {                                                                          \
            _Pragma("unroll")                                                      \
            for (int i = 0; i < 2; ++i) {                                          \
                int seg = wid*2 + i;                                               \
                int row = seg*8 + lrow;                                            \
                gload16(wt4 + (size_t)(m0 + row)*64 + (ks)*8 + lslot,              \
                        &smem[bf][seg*64]);                                        \
            }                                                                      \
            _Pragma("unroll")                                                      \
            for (int i = 0; i < 4; ++i) {                                          \
                int seg = wid*4 + i;                                               \
                int row = seg*8 + lrow;                                            \
                gload16(xt4 + (size_t)(n0 + row)*64 + (ks)*8 + lslot,              \
                        &smem[bf][512 + seg*64]);                                  \
            }                                                                      \
        }

    STAGE(0, 0);
    __syncthreads();
    int cur = 0;
    for (int ks = 0; ks < 8; ++ks) {
        if (ks < 7) STAGE(cur ^ 1, ks + 1);
        bf16x8 aH[2], aL[2], bH[4], bL[4];
        #pragma unroll
        for (int mt = 0; mt < 2; ++mt) {
            int rA = wm*32 + mt*16 + l15;
            aH[mt] = *(const bf16x8*)&smem[cur][rA*8 + ((2*g)   ^ (rA&7))];
            aL[mt] = *(const bf16x8*)&smem[cur][rA*8 + ((2*g+1) ^ (rA&7))];
        }
        #pragma unroll
        for (int nt = 0; nt < 4; ++nt) {
            int rB = wn*64 + nt*16 + l15;
            bH[nt] = *(const bf16x8*)&smem[cur][512 + rB*8 + ((2*g)   ^ (rB&7))];
            bL[nt] = *(const bf16x8*)&smem[cur][512 + rB*8 + ((2*g+1) ^ (rB&7))];
        }
        #pragma unroll
        for (int mt = 0; mt < 2; ++mt)
            #pragma unroll
            for (int nt = 0; nt < 4; ++nt) {
                acc[mt][nt] = __builtin_amdgcn_mfma_f32_16x16x32_bf16(aH[mt], bH[nt], acc[mt][nt], 0, 0, 0);
                acc[mt][nt] = __builtin_amdgcn_mfma_f32_16x16x32_bf16(aH[mt], bL[nt], acc[mt][nt], 0, 0, 0);
                acc[mt][nt] = __builtin_amdgcn_mfma_f32_16x16x32_bf16(aL[mt], bH[nt], acc[mt][nt], 0, 0, 0);
            }
        __syncthreads();
        cur ^= 1;
    }
    #undef STAGE

    const int proj = m0 >> 8;
    #pragma unroll
    for (int mt = 0; mt < 2; ++mt) {
        int chb = (m0 & 255) + wm*32 + mt*16 + 4*g;
        int ch4 = chb >> 2;
        #pragma unroll
        for (int nt = 0; nt < 4; ++nt) {
            int hw = hwb + wn*64 + nt*16 + l15;
            float* dst = ws + (size_t)proj*QSZ + (((size_t)b*64 + ch4)*HWHW + hw)*4;
            *(f32x4*)dst = acc[mt][nt];
        }
    }
}

// ---------------- Scores v3: direct-L1 register windows, 2 rows/lane ----------------
// block = (b, h-pair, cgq of 64ch); 4 waves each own 4 packed channel-groups (16ch).
// Lane = pixel w of rows h0 and h0+1. Per (ci4, kr 0..7): one 7-float4 window
// serves BOTH rows' taps (dk = kr - r). No LDS, no barriers. Global atomicAdd.
__global__ __launch_bounds__(256) void scores_v3_kernel(
    const float* __restrict__ relx,
    const float* __restrict__ rely,
    float* __restrict__ ws)
{
    const float* qbuf = ws;
    const float* kbuf = ws + QSZ;
    float* sbuf = ws + ATTNOFF;

    const int bid = blockIdx.x;
    const int cgq = bid & 3;                 // 64-ch quarter
    const int h2  = (bid >> 2) % (HH/2);
    const int b   = bid / (4*(HH/2));
    const int h0 = h2*2;

    const int tid = threadIdx.x;
    const int wv = tid >> 6;
    const int w = tid & 63;
    const bool act = (w < WW);

    float s[2][KK];
    #pragma unroll
    for (int r=0;r<2;r++)
        #pragma unroll
        for (int i=0;i<KK;i++) s[r][i]=0.f;
    float ra[2][7];
    #pragma unroll
    for (int r=0;r<2;r++)
        #pragma unroll
        for (int l=0;l<7;l++) ra[r][l]=0.f;

    const float* rel = (cgq < 2) ? relx : rely;
    const int relch0 = (cgq < 2) ? 0 : RELN;

    #pragma unroll
    for (int ci = 0; ci < 4; ++ci) {
        const int ci4 = cgq*16 + wv*4 + ci;
        const float* kb = kbuf + ((size_t)b*64 + ci4)*HWHW*4;
        // q for both rows
        f32x4 q4[2];
        #pragma unroll
        for (int r=0;r<2;r++)
            q4[r] = act ? *(const f32x4*)(qbuf + (((size_t)b*64 + ci4)*HWHW + (h0+r)*WW + w)*4)
                        : (f32x4){0.f,0.f,0.f,0.f};
        // rel bias partials (uniform rel rows)
        #pragma unroll
        for (int cc = 0; cc < 4; ++cc) {
            const float* rp = rel + (ci4*4 + cc - relch0)*7;
            #pragma unroll
            for (int l = 0; l < 7; ++l) {
                ra[0][l] += q4[0][cc] * rp[l];
                ra[1][l] += q4[1][cc] * rp[l];
            }
        }
        #pragma unroll
        for (int kr = 0; kr < 8; ++kr) {
            const int gr = h0 + kr - 3;
            const bool rok = (gr >= 0 && gr < HH);
            f32x4 vrow[7];
            #pragma unroll
            for (int jj = 0; jj < 7; ++jj) {
                const int gc = w + jj - 3;
                vrow[jj] = (act && rok && gc >= 0 && gc < WW)
                    ? *(const f32x4*)(kb + ((size_t)gr*WW + gc)*4)
                    : (f32x4){0.f,0.f,0.f,0.f};
            }
            #pragma unroll
            for (int r = 0; r < 2; ++r) {
                const int dk = kr - r;
                if (dk >= 0 && dk <= 6) {
                    #pragma unroll
                    for (int dl = 0; dl < 7; ++dl) {
                        s[r][dk*7+dl] += q4[r][0]*vrow[dl][0] + q4[r][1]*vrow[dl][1]
                                       + q4[r][2]*vrow[dl][2] + q4[r][3]*vrow[dl][3];
                    }
                }
            }
        }
    }

    if (act) {
        const int slot0 = (cgq < 2) ? 49 : 56;
        #pragma unroll
        for (int r = 0; r < 2; ++r) {
            float* base = sbuf + ((size_t)(b*HH + h0 + r)*64)*WW + w;
            #pragma unroll
            for (int i = 0; i < KK; ++i)
                atomicAdd(base + (size_t)i*WW, s[r][i]);
            #pragma unroll
            for (int l = 0; l < 7; ++l)
                atomicAdd(base + (size_t)(slot0 + l)*WW, ra[r][l]);
        }
    }
}

// ---------------- Softmax finalize (unchanged) ----------------
__global__ __launch_bounds__(64) void softmax_kernel(float* __restrict__ ws)
{
    float* sbuf = ws + ATTNOFF;
    const int p = blockIdx.x*64 + threadIdx.x;
    const int w = p % WW;
    const int h = (p / WW) % HH;
    const int b = p / (WW*HH);
    float* base = sbuf + ((size_t)(b*HH + h)*64)*WW + w;

    float tot[KK], qx[7], qy[7];
    #pragma unroll
    for (int i=0;i<KK;i++) tot[i] = base[(size_t)i*WW];
    #pragma unroll
    for (int l=0;l<7;l++) { qx[l] = base[(size_t)(49+l)*WW]; qy[l] = base[(size_t)(56+l)*WW]; }

    float mx = -1e30f;
    #pragma unroll
    for (int dk=0;dk<7;dk++) {
        #pragma unroll
        for (int dl=0;dl<7;dl++) {
            tot[dk*7+dl] += qy[dk] + qx[dl];
            mx = fmaxf(mx, tot[dk*7+dl]);
        }
    }
    float sum = 0.f;
    #pragma unroll
    for (int i=0;i<KK;i++) { float e = __expf(tot[i]-mx); tot[i]=e; sum += e; }
    float inv = 1.f/sum;
    #pragma unroll
    for (int i=0;i<KK;i++) base[(size_t)i*WW] = tot[i]*inv;
}

// ---------------- PV + bias (unchanged) ----------------
__global__ __launch_bounds__(128) void pv_kernel(
    const float* __restrict__ bias,
    const float* __restrict__ ws,
    float* __restrict__ out)
{
    const float* vbuf = ws + 2*QSZ;
    const float* attn = ws + ATTNOFF;

    const int bid = blockIdx.x;
    const int pxt = bid % 18;
    const int pgq = (bid / 18) % 16;
    const int b   = bid / (18*16);

    const int tid = threadIdx.x;
    const int pxg = tid & 31;
    const int pg  = pgq*4 + (tid >> 5);

    const int hw0 = pxt*128 + pxg*4;
    const int w0 = hw0 % WW;
    const int h0 = hw0 / WW;

    const float* vb = vbuf + ((size_t)b*64 + pg)*HWHW*4;
    const float* ab = attn + ((size_t)(b*HH + h0)*64)*WW;

    const float4 b4 = *(const float4*)(bias + pg*4);
    f32x4 bias4 = (f32x4){b4.x, b4.y, b4.z, b4.w};
    f32x4 acc[4];
    #pragma unroll
    for (int p = 0; p < 4; ++p) acc[p] = bias4;

    #pragma unroll
    for (int dk = 0; dk < 7; ++dk) {
        const int gr = h0 + dk - 3;
        const bool rok = (gr >= 0 && gr < HH);
        f32x4 vrow[10];
        #pragma unroll
        for (int jj = 0; jj < 10; ++jj) {
            const int gc = w0 - 3 + jj;
            vrow[jj] = (rok && gc >= 0 && gc < WW)
                ? *(const f32x4*)(vb + ((size_t)gr*WW + gc)*4)
                : (f32x4){0.f,0.f,0.f,0.f};
        }
        const float* arow = ab + (size_t)(dk*7)*WW + w0;
        #pragma unroll
        for (int dl = 0; dl < 7; ++dl) {
            const float4 av = *(const float4*)(arow + (size_t)dl*WW);
            acc[0] += vrow[dl+0] * av.x;
            acc[1] += vrow[dl+1] * av.y;
            acc[2] += vrow[dl+2] * av.z;
            acc[3] += vrow[dl+3] * av.w;
        }
    }
    #pragma unroll
    for (int c = 0; c < 4; ++c) {
        float4 o;
        o.x = acc[0][c]; o.y = acc[1][c]; o.z = acc[2][c]; o.w = acc[3][c];
        *(float4*)(out + ((size_t)b*CC + pg*4 + c)*HWHW + hw0) = o;
    }
}

extern "C" void kernel_launch(void* const* d_in, const int* in_sizes, int n_in,
                              void* d_out, int out_size, void* d_ws, size_t ws_size,
                              hipStream_t stream) {
    const float* x    = (const float*)d_in[0];
    const float* wq   = (const float*)d_in[1];
    const float* wk   = (const float*)d_in[2];
    const float* wv   = (const float*)d_in[3];
    const float* bias = (const float*)d_in[4];
    const float* relx = (const float*)d_in[5];
    const float* rely = (const float*)d_in[6];
    float* ws  = (float*)d_ws;
    float* out = (float*)d_out;
    unsigned short* xt = (unsigned short*)d_out;
    unsigned short* wt = (unsigned short*)(ws + WTOFF);

    prep_kernel<<<dim3(960), dim3(256), 0, stream>>>(x, wq, wk, wv, xt, wt, ws);
    proj_gemm_kernel<<<dim3(72, 12), dim3(256), 0, stream>>>(xt, wt, ws);
    scores_v3_kernel<<<dim3(BB*(HH/2)*4), dim3(256), 0, stream>>>(relx, rely, ws);
    softmax_kernel<<<dim3(144), dim3(64), 0, stream>>>(ws);
    pv_kernel<<<dim3(BB*16*18), dim3(128), 0, stream>>>(bias, ws, out);
}

// Round 10
// 83.674 us; speedup vs baseline: 3.1788x; 3.1788x over previous
//
#include <hip/hip_runtime.h>

#define BB 4
#define CC 256
#define HH 48
#define WW 48
#define HWHW 2304
#define KK 49
#define RELN 128

// ws layout (floats): q | k | v | sbuf | WT
// q,k,v channel-packed: [b][c/4][h][w][4]
#define QSZ (BB*CC*HWHW)            // 2359296 floats per tensor
#define ATTNOFF (3*QSZ)             // sbuf: [B][H][64][W] (taps 0-48, qx 49-55, qy 56-62)
#define SBUF_FLOATS (BB*HH*64*WW)   // 589824
#define WTOFF (ATTNOFF + SBUF_FLOATS)
// XT (bf16 hi/lo of x, PRE-SWIZZLED chunks) lives in d_out

typedef short bf16x8 __attribute__((ext_vector_type(8)));
typedef float f32x4 __attribute__((ext_vector_type(4)));

__device__ __forceinline__ void split_bf16(float f, unsigned short& hi, unsigned short& lo)
{
    unsigned u = __float_as_uint(f);
    hi = (unsigned short)(u >> 16);
    float r = f - __uint_as_float(u & 0xFFFF0000u);
    unsigned v = __float_as_uint(r);
    v += 0x7FFFu + ((v >> 16) & 1u);
    lo = (unsigned short)(v >> 16);
}

__device__ __forceinline__ void gload16(const uint4* g, uint4* l)
{
    __builtin_amdgcn_global_load_lds(
        (const __attribute__((address_space(1))) void*)g,
        (__attribute__((address_space(3))) void*)l, 16, 0, 0);
}

// ---------------- prep: zero sbuf | convert x -> XT | convert w -> WT ----------------
__global__ __launch_bounds__(256) void prep_kernel(
    const float* __restrict__ x,
    const float* __restrict__ wq, const float* __restrict__ wk,
    const float* __restrict__ wvp,
    unsigned short* __restrict__ xt, unsigned short* __restrict__ wt,
    float* __restrict__ ws)
{
    __shared__ unsigned short lds[32*520];
    const int bid = blockIdx.x;
    const int t = threadIdx.x;

    if (bid < 576) {                       // zero sbuf
        float4* p = (float4*)(ws + ATTNOFF);
        p[bid*256 + t] = make_float4(0.f,0.f,0.f,0.f);
        return;
    }
    if (bid < 864) {                       // convert_x, 288 blocks
        const int bid2 = bid - 576;
        const int b = bid2 / 72;
        const int hw0 = (bid2 % 72) * 32;
        const int hw = t & 31, cp = t >> 5;
        #pragma unroll 4
        for (int i = 0; i < 32; ++i) {
            int c = i*8 + cp;
            float f = x[((size_t)b*CC + c)*HWHW + hw0 + hw];
            unsigned short hi, lo; split_bf16(f, hi, lo);
            int ch = i*2;
            lds[hw*520 + ((ch       ^ (hw&7))*8) + cp] = hi;
            lds[hw*520 + (((ch + 1) ^ (hw&7))*8) + cp] = lo;
        }
        __syncthreads();
        const int hw2 = t >> 3, u = t & 7;
        uint4* xt4 = (uint4*)xt;
        const size_t rowbase = ((size_t)b*HWHW + hw0 + hw2) * 64;
        #pragma unroll
        for (int j = 0; j < 8; ++j) {
            int chunk = j*8 + u;
            uint4 v = *(const uint4*)&lds[hw2*520 + chunk*8];
            xt4[rowbase + chunk] = v;
        }
        return;
    }
    {                                       // convert_w, 96 blocks
        const int tt = (bid - 864)*256 + t;
        const int m = tt >> 5, kg = tt & 31;
        const float* src = (m < 256) ? wq : (m < 512) ? wk : wvp;
        const float* row = src + (size_t)(m & 255)*256 + kg*8;
        unsigned short h[8], l[8];
        #pragma unroll
        for (int j = 0; j < 8; ++j) split_bf16(row[j], h[j], l[j]);
        uint4 hv, lv;
        hv.x = (unsigned)h[0] | ((unsigned)h[1]<<16); hv.y = (unsigned)h[2] | ((unsigned)h[3]<<16);
        hv.z = (unsigned)h[4] | ((unsigned)h[5]<<16); hv.w = (unsigned)h[6] | ((unsigned)h[7]<<16);
        lv.x = (unsigned)l[0] | ((unsigned)l[1]<<16); lv.y = (unsigned)l[2] | ((unsigned)l[3]<<16);
        lv.z = (unsigned)l[4] | ((unsigned)l[5]<<16); lv.w = (unsigned)l[6] | ((unsigned)l[7]<<16);
        uint4* dstrow = (uint4*)wt + (size_t)m*64;
        const int ks = kg >> 2, s_hi = 2*(kg & 3);
        dstrow[ks*8 + ( s_hi      ^ (m&7))] = hv;
        dstrow[ks*8 + ((s_hi + 1) ^ (m&7))] = lv;
    }
}

// ---------------- Projection GEMM: split-bf16 MFMA, gload_lds 2-phase, BM=BN=64 ----------------
// C[768][9216] = W[768][256] x X[256][9216]; 3 passes hi*hi + hi*lo + lo*hi.
// Grid 144x12 = 1728 blocks (6.75/CU), LDS 2x16KB -> 5 blocks/CU resident.
__global__ __launch_bounds__(256) void proj_gemm_kernel(
    const unsigned short* __restrict__ xt,
    const unsigned short* __restrict__ wt,
    float* __restrict__ ws)
{
    __shared__ uint4 smem[2][1024];          // per buf: A 512 | B 512 uint4 = 16KB
    const int n0 = blockIdx.x * 64;
    const int m0 = blockIdx.y * 64;
    const int b = n0 / HWHW;
    const int hwb = n0 % HWHW;
    const int tid = threadIdx.x;
    const int wid = tid >> 6, ln = tid & 63;
    const int wm = wid >> 1, wn = wid & 1;
    const int l15 = ln & 15, g = ln >> 4;

    f32x4 acc[2][2];
    #pragma unroll
    for (int i = 0; i < 2; ++i)
        #pragma unroll
        for (int j = 0; j < 2; ++j) acc[i][j] = (f32x4){0.f,0.f,0.f,0.f};

    const uint4* wt4 = (const uint4*)wt;
    const uint4* xt4 = (const uint4*)xt;
    const int lrow = ln >> 3, lslot = ln & 7;

    // stage K-step ks into buffer bf: each wave copies 2 A-segs + 2 B-segs (1KB each)
    #define STAGE(bf, ks)                                                          \
        {                                                                          \
            _Pragma("unroll")                                                      \
            for (int i = 0; i < 2; ++i) {                                          \
                int seg = wid*2 + i;                                               \
                int row = seg*8 + lrow;                                            \
                gload16(wt4 + (size_t)(m0 + row)*64 + (ks)*8 + lslot,              \
                        &smem[bf][seg*64]);                                        \
                gload16(xt4 + (size_t)(n0 + row)*64 + (ks)*8 + lslot,              \
                        &smem[bf][512 + seg*64]);                                  \
            }                                                                      \
        }

    STAGE(0, 0);
    __syncthreads();                          // drains vmcnt: buf0 ready
    int cur = 0;
    for (int ks = 0; ks < 8; ++ks) {
        if (ks < 7) STAGE(cur ^ 1, ks + 1);   // issue next tile (no wait)
        bf16x8 aH[2], aL[2], bH[2], bL[2];
        #pragma unroll
        for (int mt = 0; mt < 2; ++mt) {
            int rA = wm*32 + mt*16 + l15;
            aH[mt] = *(const bf16x8*)&smem[cur][rA*8 + ((2*g)   ^ (rA&7))];
            aL[mt] = *(const bf16x8*)&smem[cur][rA*8 + ((2*g+1) ^ (rA&7))];
        }
        #pragma unroll
        for (int nt = 0; nt < 2; ++nt) {
            int rB = wn*32 + nt*16 + l15;
            bH[nt] = *(const bf16x8*)&smem[cur][512 + rB*8 + ((2*g)   ^ (rB&7))];
            bL[nt] = *(const bf16x8*)&smem[cur][512 + rB*8 + ((2*g+1) ^ (rB&7))];
        }
        #pragma unroll
        for (int mt = 0; mt < 2; ++mt)
            #pragma unroll
            for (int nt = 0; nt < 2; ++nt) {
                acc[mt][nt] = __builtin_amdgcn_mfma_f32_16x16x32_bf16(aH[mt], bH[nt], acc[mt][nt], 0, 0, 0);
                acc[mt][nt] = __builtin_amdgcn_mfma_f32_16x16x32_bf16(aH[mt], bL[nt], acc[mt][nt], 0, 0, 0);
                acc[mt][nt] = __builtin_amdgcn_mfma_f32_16x16x32_bf16(aL[mt], bH[nt], acc[mt][nt], 0, 0, 0);
            }
        __syncthreads();                      // drain staged loads + reads of cur
        cur ^= 1;
    }
    #undef STAGE

    // epilogue: C/D layout col=lane&15, row=4*(lane>>4)+reg -> channel-packed float4
    const int proj = m0 >> 8;
    #pragma unroll
    for (int mt = 0; mt < 2; ++mt) {
        int chb = (m0 & 255) + wm*32 + mt*16 + 4*g;
        int ch4 = chb >> 2;
        #pragma unroll
        for (int nt = 0; nt < 2; ++nt) {
            int hw = hwb + wn*32 + nt*16 + l15;
            float* dst = ws + (size_t)proj*QSZ + (((size_t)b*64 + ch4)*HWHW + hw)*4;
            *(f32x4*)dst = acc[mt][nt];
        }
    }
}

// ---------------- Scores partial (R8 version, reverted) ----------------
__global__ __launch_bounds__(256) void scores_partial_kernel(
    const float* __restrict__ relx,
    const float* __restrict__ rely,
    float* __restrict__ ws)
{
    const float* qbuf = ws;
    const float* kbuf = ws + QSZ;
    float* sbuf = ws + ATTNOFF;

    __shared__ float ks[4][7][56][4];

    const int bid = blockIdx.x;
    const int cg8 = bid & 7;
    const int h  = (bid >> 3) % HH;
    const int b  = bid / (8*HH);

    const int tid = threadIdx.x;
    const int wv = tid >> 6;
    const int w = tid & 63;
    const bool act = (w < WW);

    float s[14];
    #pragma unroll
    for (int i=0;i<14;i++) s[i]=0.f;

    const float* rel = (cg8 < 4) ? relx : rely;
    const int relch0 = (cg8 < 4) ? 0 : RELN;

    for (int chunk = 0; chunk < 2; ++chunk) {
        const int cq0 = cg8*8 + chunk*4;
        #pragma unroll
        for (int t = 0; t < 6; ++t) {
            int fi = tid + t*256;
            if (fi < 1512) {
                int ci4 = fi / 378;
                int rem = fi - ci4*378;
                int rw = rem / 54;
                int cl = rem - rw*54;
                int gr = h + rw - 3;
                int gc = cl - 3;
                float4 v = make_float4(0.f,0.f,0.f,0.f);
                if (gr >= 0 && gr < HH && gc >= 0 && gc < WW)
                    v = *(const float4*)(kbuf
                        + (((size_t)b*64 + cq0 + ci4)*HWHW + gr*WW + gc)*4);
                *(float4*)&ks[ci4][rw][cl][0] = v;
            }
        }
        __syncthreads();
        if (act) {
            #pragma unroll
            for (int ci4 = 0; ci4 < 4; ++ci4) {
                const float4 q4 = *(const float4*)(qbuf
                    + (((size_t)b*64 + cq0 + ci4)*HWHW + h*WW + w)*4);
                const float qa[4] = {q4.x, q4.y, q4.z, q4.w};
                if (wv < 3) {
                    #pragma unroll
                    for (int dd = 0; dd < 2; ++dd) {
                        const int row = wv*2 + dd;
                        #pragma unroll
                        for (int dl = 0; dl < 7; ++dl) {
                            const float4 kv = *(const float4*)&ks[ci4][row][w + dl][0];
                            s[dd*7+dl] += qa[0]*kv.x + qa[1]*kv.y + qa[2]*kv.z + qa[3]*kv.w;
                        }
                    }
                } else {
                    #pragma unroll
                    for (int dl = 0; dl < 7; ++dl) {
                        const float4 kv = *(const float4*)&ks[ci4][6][w + dl][0];
                        s[dl] += qa[0]*kv.x + qa[1]*kv.y + qa[2]*kv.z + qa[3]*kv.w;
                    }
                    #pragma unroll
                    for (int cc = 0; cc < 4; ++cc) {
                        const int ch = (cq0 + ci4)*4 + cc;
                        const float* rp = rel + (ch - relch0)*7;
                        #pragma unroll
                        for (int l = 0; l < 7; ++l)
                            s[7+l] += qa[cc] * rp[l];
                    }
                }
            }
        }
        __syncthreads();
    }

    if (act) {
        float* base = sbuf + ((size_t)(b*HH + h)*64)*WW + w;
        if (wv < 3) {
            #pragma unroll
            for (int i = 0; i < 14; ++i)
                atomicAdd(base + (size_t)(wv*14 + i)*WW, s[i]);
        } else {
            #pragma unroll
            for (int i = 0; i < 7; ++i)
                atomicAdd(base + (size_t)(42 + i)*WW, s[i]);
            const int slot0 = (cg8 < 4) ? 49 : 56;
            #pragma unroll
            for (int l = 0; l < 7; ++l)
                atomicAdd(base + (size_t)(slot0 + l)*WW, s[7+l]);
        }
    }
}

// ---------------- Softmax finalize (unchanged) ----------------
__global__ __launch_bounds__(64) void softmax_kernel(float* __restrict__ ws)
{
    float* sbuf = ws + ATTNOFF;
    const int p = blockIdx.x*64 + threadIdx.x;
    const int w = p % WW;
    const int h = (p / WW) % HH;
    const int b = p / (WW*HH);
    float* base = sbuf + ((size_t)(b*HH + h)*64)*WW + w;

    float tot[KK], qx[7], qy[7];
    #pragma unroll
    for (int i=0;i<KK;i++) tot[i] = base[(size_t)i*WW];
    #pragma unroll
    for (int l=0;l<7;l++) { qx[l] = base[(size_t)(49+l)*WW]; qy[l] = base[(size_t)(56+l)*WW]; }

    float mx = -1e30f;
    #pragma unroll
    for (int dk=0;dk<7;dk++) {
        #pragma unroll
        for (int dl=0;dl<7;dl++) {
            tot[dk*7+dl] += qy[dk] + qx[dl];
            mx = fmaxf(mx, tot[dk*7+dl]);
        }
    }
    float sum = 0.f;
    #pragma unroll
    for (int i=0;i<KK;i++) { float e = __expf(tot[i]-mx); tot[i]=e; sum += e; }
    float inv = 1.f/sum;
    #pragma unroll
    for (int i=0;i<KK;i++) base[(size_t)i*WW] = tot[i]*inv;
}

// ---------------- PV + bias (unchanged) ----------------
__global__ __launch_bounds__(128) void pv_kernel(
    const float* __restrict__ bias,
    const float* __restrict__ ws,
    float* __restrict__ out)
{
    const float* vbuf = ws + 2*QSZ;
    const float* attn = ws + ATTNOFF;

    const int bid = blockIdx.x;
    const int pxt = bid % 18;
    const int pgq = (bid / 18) % 16;
    const int b   = bid / (18*16);

    const int tid = threadIdx.x;
    const int pxg = tid & 31;
    const int pg  = pgq*4 + (tid >> 5);

    const int hw0 = pxt*128 + pxg*4;
    const int w0 = hw0 % WW;
    const int h0 = hw0 / WW;

    const float* vb = vbuf + ((size_t)b*64 + pg)*HWHW*4;
    const float* ab = attn + ((size_t)(b*HH + h0)*64)*WW;

    const float4 b4 = *(const float4*)(bias + pg*4);
    f32x4 bias4 = (f32x4){b4.x, b4.y, b4.z, b4.w};
    f32x4 acc[4];
    #pragma unroll
    for (int p = 0; p < 4; ++p) acc[p] = bias4;

    #pragma unroll
    for (int dk = 0; dk < 7; ++dk) {
        const int gr = h0 + dk - 3;
        const bool rok = (gr >= 0 && gr < HH);
        f32x4 vrow[10];
        #pragma unroll
        for (int jj = 0; jj < 10; ++jj) {
            const int gc = w0 - 3 + jj;
            vrow[jj] = (rok && gc >= 0 && gc < WW)
                ? *(const f32x4*)(vb + ((size_t)gr*WW + gc)*4)
                : (f32x4){0.f,0.f,0.f,0.f};
        }
        const float* arow = ab + (size_t)(dk*7)*WW + w0;
        #pragma unroll
        for (int dl = 0; dl < 7; ++dl) {
            const float4 av = *(const float4*)(arow + (size_t)dl*WW);
            acc[0] += vrow[dl+0] * av.x;
            acc[1] += vrow[dl+1] * av.y;
            acc[2] += vrow[dl+2] * av.z;
            acc[3] += vrow[dl+3] * av.w;
        }
    }
    #pragma unroll
    for (int c = 0; c < 4; ++c) {
        float4 o;
        o.x = acc[0][c]; o.y = acc[1][c]; o.z = acc[2][c]; o.w = acc[3][c];
        *(float4*)(out + ((size_t)b*CC + pg*4 + c)*HWHW + hw0) = o;
    }
}

extern "C" void kernel_launch(void* const* d_in, const int* in_sizes, int n_in,
                              void* d_out, int out_size, void* d_ws, size_t ws_size,
                              hipStream_t stream) {
    const float* x    = (const float*)d_in[0];
    const float* wq   = (const float*)d_in[1];
    const float* wk   = (const float*)d_in[2];
    const float* wv   = (const float*)d_in[3];
    const float* bias = (const float*)d_in[4];
    const float* relx = (const float*)d_in[5];
    const float* rely = (const float*)d_in[6];
    float* ws  = (float*)d_ws;
    float* out = (float*)d_out;
    unsigned short* xt = (unsigned short*)d_out;
    unsigned short* wt = (unsigned short*)(ws + WTOFF);

    prep_kernel<<<dim3(960), dim3(256), 0, stream>>>(x, wq, wk, wv, xt, wt, ws);
    proj_gemm_kernel<<<dim3(144, 12), dim3(256), 0, stream>>>(xt, wt, ws);
    scores_partial_kernel<<<dim3(BB*HH*8), dim3(256), 0, stream>>>(relx, rely, ws);
    softmax_kernel<<<dim3(144), dim3(64), 0, stream>>>(ws);
    pv_kernel<<<dim3(BB*16*18), dim3(128), 0, stream>>>(bias, ws, out);
}

// Round 11
// 83.405 us; speedup vs baseline: 3.1890x; 1.0032x over previous
//
#include <hip/hip_runtime.h>

#define BB 4
#define CC 256
#define HH 48
#define WW 48
#define HWHW 2304
#define KK 49
#define RELN 128

// ws layout (floats): q | k | v | sbuf | WT | PART
// q,k,v channel-packed: [b][c/4][h][w][4]
#define QSZ (BB*CC*HWHW)            // 2359296 floats per tensor
#define ATTNOFF (3*QSZ)             // sbuf: [B][H][64][W] (taps 0-48 = attn after reduce)
#define SBUF_FLOATS (BB*HH*64*WW)   // 589824
#define WTOFF (ATTNOFF + SBUF_FLOATS)
#define WT_FLOATS 196608            // 768*512 u16
#define PARTOFF (WTOFF + WT_FLOATS) // part: [B*H][64 slots][8 cg8][48 w] = 4718592 floats
// XT (bf16 hi/lo of x, PRE-SWIZZLED chunks) lives in d_out

typedef short bf16x8 __attribute__((ext_vector_type(8)));
typedef float f32x4 __attribute__((ext_vector_type(4)));

__device__ __forceinline__ void split_bf16(float f, unsigned short& hi, unsigned short& lo)
{
    unsigned u = __float_as_uint(f);
    hi = (unsigned short)(u >> 16);
    float r = f - __uint_as_float(u & 0xFFFF0000u);
    unsigned v = __float_as_uint(r);
    v += 0x7FFFu + ((v >> 16) & 1u);
    lo = (unsigned short)(v >> 16);
}

__device__ __forceinline__ void gload16(const uint4* g, uint4* l)
{
    __builtin_amdgcn_global_load_lds(
        (const __attribute__((address_space(1))) void*)g,
        (__attribute__((address_space(3))) void*)l, 16, 0, 0);
}

// ---------------- prep: convert x -> XT | convert w -> WT ----------------
__global__ __launch_bounds__(256) void prep_kernel(
    const float* __restrict__ x,
    const float* __restrict__ wq, const float* __restrict__ wk,
    const float* __restrict__ wvp,
    unsigned short* __restrict__ xt, unsigned short* __restrict__ wt)
{
    __shared__ unsigned short lds[32*520];
    const int bid = blockIdx.x;
    const int t = threadIdx.x;

    if (bid < 288) {                       // convert_x, 288 blocks
        const int b = bid / 72;
        const int hw0 = (bid % 72) * 32;
        const int hw = t & 31, cp = t >> 5;
        #pragma unroll 4
        for (int i = 0; i < 32; ++i) {
            int c = i*8 + cp;
            float f = x[((size_t)b*CC + c)*HWHW + hw0 + hw];
            unsigned short hi, lo; split_bf16(f, hi, lo);
            int ch = i*2;
            lds[hw*520 + ((ch       ^ (hw&7))*8) + cp] = hi;
            lds[hw*520 + (((ch + 1) ^ (hw&7))*8) + cp] = lo;
        }
        __syncthreads();
        const int hw2 = t >> 3, u = t & 7;
        uint4* xt4 = (uint4*)xt;
        const size_t rowbase = ((size_t)b*HWHW + hw0 + hw2) * 64;
        #pragma unroll
        for (int j = 0; j < 8; ++j) {
            int chunk = j*8 + u;
            uint4 v = *(const uint4*)&lds[hw2*520 + chunk*8];
            xt4[rowbase + chunk] = v;
        }
        return;
    }
    {                                       // convert_w, 96 blocks
        const int tt = (bid - 288)*256 + t;
        const int m = tt >> 5, kg = tt & 31;
        const float* src = (m < 256) ? wq : (m < 512) ? wk : wvp;
        const float* row = src + (size_t)(m & 255)*256 + kg*8;
        unsigned short h[8], l[8];
        #pragma unroll
        for (int j = 0; j < 8; ++j) split_bf16(row[j], h[j], l[j]);
        uint4 hv, lv;
        hv.x = (unsigned)h[0] | ((unsigned)h[1]<<16); hv.y = (unsigned)h[2] | ((unsigned)h[3]<<16);
        hv.z = (unsigned)h[4] | ((unsigned)h[5]<<16); hv.w = (unsigned)h[6] | ((unsigned)h[7]<<16);
        lv.x = (unsigned)l[0] | ((unsigned)l[1]<<16); lv.y = (unsigned)l[2] | ((unsigned)l[3]<<16);
        lv.z = (unsigned)l[4] | ((unsigned)l[5]<<16); lv.w = (unsigned)l[6] | ((unsigned)l[7]<<16);
        uint4* dstrow = (uint4*)wt + (size_t)m*64;
        const int ks = kg >> 2, s_hi = 2*(kg & 3);
        dstrow[ks*8 + ( s_hi      ^ (m&7))] = hv;
        dstrow[ks*8 + ((s_hi + 1) ^ (m&7))] = lv;
    }
}

// ---------------- Projection GEMM (unchanged from R10) ----------------
__global__ __launch_bounds__(256) void proj_gemm_kernel(
    const unsigned short* __restrict__ xt,
    const unsigned short* __restrict__ wt,
    float* __restrict__ ws)
{
    __shared__ uint4 smem[2][1024];
    const int n0 = blockIdx.x * 64;
    const int m0 = blockIdx.y * 64;
    const int b = n0 / HWHW;
    const int hwb = n0 % HWHW;
    const int tid = threadIdx.x;
    const int wid = tid >> 6, ln = tid & 63;
    const int wm = wid >> 1, wn = wid & 1;
    const int l15 = ln & 15, g = ln >> 4;

    f32x4 acc[2][2];
    #pragma unroll
    for (int i = 0; i < 2; ++i)
        #pragma unroll
        for (int j = 0; j < 2; ++j) acc[i][j] = (f32x4){0.f,0.f,0.f,0.f};

    const uint4* wt4 = (const uint4*)wt;
    const uint4* xt4 = (const uint4*)xt;
    const int lrow = ln >> 3, lslot = ln & 7;

    #define STAGE(bf, ks)                                                          \
        {                                                                          \
            _Pragma("unroll")                                                      \
            for (int i = 0; i < 2; ++i) {                                          \
                int seg = wid*2 + i;                                               \
                int row = seg*8 + lrow;                                            \
                gload16(wt4 + (size_t)(m0 + row)*64 + (ks)*8 + lslot,              \
                        &smem[bf][seg*64]);                                        \
                gload16(xt4 + (size_t)(n0 + row)*64 + (ks)*8 + lslot,              \
                        &smem[bf][512 + seg*64]);                                  \
            }                                                                      \
        }

    STAGE(0, 0);
    __syncthreads();
    int cur = 0;
    for (int ks = 0; ks < 8; ++ks) {
        if (ks < 7) STAGE(cur ^ 1, ks + 1);
        bf16x8 aH[2], aL[2], bH[2], bL[2];
        #pragma unroll
        for (int mt = 0; mt < 2; ++mt) {
            int rA = wm*32 + mt*16 + l15;
            aH[mt] = *(const bf16x8*)&smem[cur][rA*8 + ((2*g)   ^ (rA&7))];
            aL[mt] = *(const bf16x8*)&smem[cur][rA*8 + ((2*g+1) ^ (rA&7))];
        }
        #pragma unroll
        for (int nt = 0; nt < 2; ++nt) {
            int rB = wn*32 + nt*16 + l15;
            bH[nt] = *(const bf16x8*)&smem[cur][512 + rB*8 + ((2*g)   ^ (rB&7))];
            bL[nt] = *(const bf16x8*)&smem[cur][512 + rB*8 + ((2*g+1) ^ (rB&7))];
        }
        #pragma unroll
        for (int mt = 0; mt < 2; ++mt)
            #pragma unroll
            for (int nt = 0; nt < 2; ++nt) {
                acc[mt][nt] = __builtin_amdgcn_mfma_f32_16x16x32_bf16(aH[mt], bH[nt], acc[mt][nt], 0, 0, 0);
                acc[mt][nt] = __builtin_amdgcn_mfma_f32_16x16x32_bf16(aH[mt], bL[nt], acc[mt][nt], 0, 0, 0);
                acc[mt][nt] = __builtin_amdgcn_mfma_f32_16x16x32_bf16(aL[mt], bH[nt], acc[mt][nt], 0, 0, 0);
            }
        __syncthreads();
        cur ^= 1;
    }
    #undef STAGE

    const int proj = m0 >> 8;
    #pragma unroll
    for (int mt = 0; mt < 2; ++mt) {
        int chb = (m0 & 255) + wm*32 + mt*16 + 4*g;
        int ch4 = chb >> 2;
        #pragma unroll
        for (int nt = 0; nt < 2; ++nt) {
            int hw = hwb + wn*32 + nt*16 + l15;
            float* dst = ws + (size_t)proj*QSZ + (((size_t)b*64 + ch4)*HWHW + hw)*4;
            *(f32x4*)dst = acc[mt][nt];
        }
    }
}

// ---------------- Scores partial: NO atomics, private slab ----------------
// block = (b, h, cg8); writes s[14] to part[bh][slot][cg8][w] (coalesced stores).
__global__ __launch_bounds__(256) void scores_partial_kernel(
    const float* __restrict__ relx,
    const float* __restrict__ rely,
    float* __restrict__ ws)
{
    const float* qbuf = ws;
    const float* kbuf = ws + QSZ;
    float* part = ws + PARTOFF;

    __shared__ float ks[4][7][56][4];

    const int bid = blockIdx.x;
    const int cg8 = bid & 7;
    const int h  = (bid >> 3) % HH;
    const int b  = bid / (8*HH);

    const int tid = threadIdx.x;
    const int wv = tid >> 6;
    const int w = tid & 63;
    const bool act = (w < WW);

    float s[14];
    #pragma unroll
    for (int i=0;i<14;i++) s[i]=0.f;

    const float* rel = (cg8 < 4) ? relx : rely;
    const int relch0 = (cg8 < 4) ? 0 : RELN;

    for (int chunk = 0; chunk < 2; ++chunk) {
        const int cq0 = cg8*8 + chunk*4;
        #pragma unroll
        for (int t = 0; t < 6; ++t) {
            int fi = tid + t*256;
            if (fi < 1512) {
                int ci4 = fi / 378;
                int rem = fi - ci4*378;
                int rw = rem / 54;
                int cl = rem - rw*54;
                int gr = h + rw - 3;
                int gc = cl - 3;
                float4 v = make_float4(0.f,0.f,0.f,0.f);
                if (gr >= 0 && gr < HH && gc >= 0 && gc < WW)
                    v = *(const float4*)(kbuf
                        + (((size_t)b*64 + cq0 + ci4)*HWHW + gr*WW + gc)*4);
                *(float4*)&ks[ci4][rw][cl][0] = v;
            }
        }
        __syncthreads();
        if (act) {
            #pragma unroll
            for (int ci4 = 0; ci4 < 4; ++ci4) {
                const float4 q4 = *(const float4*)(qbuf
                    + (((size_t)b*64 + cq0 + ci4)*HWHW + h*WW + w)*4);
                const float qa[4] = {q4.x, q4.y, q4.z, q4.w};
                if (wv < 3) {
                    #pragma unroll
                    for (int dd = 0; dd < 2; ++dd) {
                        const int row = wv*2 + dd;
                        #pragma unroll
                        for (int dl = 0; dl < 7; ++dl) {
                            const float4 kv = *(const float4*)&ks[ci4][row][w + dl][0];
                            s[dd*7+dl] += qa[0]*kv.x + qa[1]*kv.y + qa[2]*kv.z + qa[3]*kv.w;
                        }
                    }
                } else {
                    #pragma unroll
                    for (int dl = 0; dl < 7; ++dl) {
                        const float4 kv = *(const float4*)&ks[ci4][6][w + dl][0];
                        s[dl] += qa[0]*kv.x + qa[1]*kv.y + qa[2]*kv.z + qa[3]*kv.w;
                    }
                    #pragma unroll
                    for (int cc = 0; cc < 4; ++cc) {
                        const int ch = (cq0 + ci4)*4 + cc;
                        const float* rp = rel + (ch - relch0)*7;
                        #pragma unroll
                        for (int l = 0; l < 7; ++l)
                            s[7+l] += qa[cc] * rp[l];
                    }
                }
            }
        }
        __syncthreads();
    }

    if (act) {
        // part[bh][slot][cg8][w]: slot stride = 8*48 = 384 floats
        float* base = part + ((size_t)(b*HH + h)*64*8 + cg8)*WW + w;
        if (wv < 3) {
            #pragma unroll
            for (int i = 0; i < 14; ++i)
                base[(size_t)(wv*14 + i)*384] = s[i];
        } else {
            #pragma unroll
            for (int i = 0; i < 7; ++i)
                base[(size_t)(42 + i)*384] = s[i];
            const int slot0 = (cg8 < 4) ? 49 : 56;
            #pragma unroll
            for (int l = 0; l < 7; ++l)
                base[(size_t)(slot0 + l)*384] = s[7+l];
        }
    }
}

// ---------------- Reduce partials + softmax ----------------
// block = (b,h). Phase 1: 256 threads reduce 8 cg8-partials -> LDS red[63][48].
// Phase 2: threads 0..47 do per-pixel softmax -> sbuf[bh][tap][w].
__global__ __launch_bounds__(256) void reduce_softmax_kernel(float* __restrict__ ws)
{
    float* part = ws + PARTOFF;
    float* sbuf = ws + ATTNOFF;
    __shared__ float red[63][48];

    const int bh = blockIdx.x;
    const int t = threadIdx.x;
    const float* pb = part + (size_t)bh*64*8*WW;

    for (int u = t; u < 63*12; u += 256) {
        const int slot = u / 12, w4 = u % 12;
        const f32x4* src = (const f32x4*)(pb + (size_t)slot*384 + w4*4);
        const int c0 = (slot < 56) ? 0 : 4;
        const int c1 = (slot < 49) ? 8 : ((slot < 56) ? 4 : 8);
        f32x4 acc = (f32x4){0.f,0.f,0.f,0.f};
        for (int c = c0; c < c1; ++c)
            acc += src[c*12];                  // cg8 stride = 48 floats = 12 f32x4
        *(f32x4*)&red[slot][w4*4] = acc;
    }
    __syncthreads();

    if (t < WW) {
        const int w = t;
        float tot[KK], qx[7], qy[7];
        #pragma unroll
        for (int i=0;i<KK;i++) tot[i] = red[i][w];
        #pragma unroll
        for (int l=0;l<7;l++) { qx[l] = red[49+l][w]; qy[l] = red[56+l][w]; }
        float mx = -1e30f;
        #pragma unroll
        for (int dk=0;dk<7;dk++) {
            #pragma unroll
            for (int dl=0;dl<7;dl++) {
                tot[dk*7+dl] += qy[dk] + qx[dl];
                mx = fmaxf(mx, tot[dk*7+dl]);
            }
        }
        float sum = 0.f;
        #pragma unroll
        for (int i=0;i<KK;i++) { float e = __expf(tot[i]-mx); tot[i]=e; sum += e; }
        float inv = 1.f/sum;
        float* base = sbuf + (size_t)bh*64*WW + w;
        #pragma unroll
        for (int i=0;i<KK;i++) base[(size_t)i*WW] = tot[i]*inv;
    }
}

// ---------------- PV + bias (unchanged) ----------------
__global__ __launch_bounds__(128) void pv_kernel(
    const float* __restrict__ bias,
    const float* __restrict__ ws,
    float* __restrict__ out)
{
    const float* vbuf = ws + 2*QSZ;
    const float* attn = ws + ATTNOFF;

    const int bid = blockIdx.x;
    const int pxt = bid % 18;
    const int pgq = (bid / 18) % 16;
    const int b   = bid / (18*16);

    const int tid = threadIdx.x;
    const int pxg = tid & 31;
    const int pg  = pgq*4 + (tid >> 5);

    const int hw0 = pxt*128 + pxg*4;
    const int w0 = hw0 % WW;
    const int h0 = hw0 / WW;

    const float* vb = vbuf + ((size_t)b*64 + pg)*HWHW*4;
    const float* ab = attn + ((size_t)(b*HH + h0)*64)*WW;

    const float4 b4 = *(const float4*)(bias + pg*4);
    f32x4 bias4 = (f32x4){b4.x, b4.y, b4.z, b4.w};
    f32x4 acc[4];
    #pragma unroll
    for (int p = 0; p < 4; ++p) acc[p] = bias4;

    #pragma unroll
    for (int dk = 0; dk < 7; ++dk) {
        const int gr = h0 + dk - 3;
        const bool rok = (gr >= 0 && gr < HH);
        f32x4 vrow[10];
        #pragma unroll
        for (int jj = 0; jj < 10; ++jj) {
            const int gc = w0 - 3 + jj;
            vrow[jj] = (rok && gc >= 0 && gc < WW)
                ? *(const f32x4*)(vb + ((size_t)gr*WW + gc)*4)
                : (f32x4){0.f,0.f,0.f,0.f};
        }
        const float* arow = ab + (size_t)(dk*7)*WW + w0;
        #pragma unroll
        for (int dl = 0; dl < 7; ++dl) {
            const float4 av = *(const float4*)(arow + (size_t)dl*WW);
            acc[0] += vrow[dl+0] * av.x;
            acc[1] += vrow[dl+1] * av.y;
            acc[2] += vrow[dl+2] * av.z;
            acc[3] += vrow[dl+3] * av.w;
        }
    }
    #pragma unroll
    for (int c = 0; c < 4; ++c) {
        float4 o;
        o.x = acc[0][c]; o.y = acc[1][c]; o.z = acc[2][c]; o.w = acc[3][c];
        *(float4*)(out + ((size_t)b*CC + pg*4 + c)*HWHW + hw0) = o;
    }
}

extern "C" void kernel_launch(void* const* d_in, const int* in_sizes, int n_in,
                              void* d_out, int out_size, void* d_ws, size_t ws_size,
                              hipStream_t stream) {
    const float* x    = (const float*)d_in[0];
    const float* wq   = (const float*)d_in[1];
    const float* wk   = (const float*)d_in[2];
    const float* wv   = (const float*)d_in[3];
    const float* bias = (const float*)d_in[4];
    const float* relx = (const float*)d_in[5];
    const float* rely = (const float*)d_in[6];
    float* ws  = (float*)d_ws;
    float* out = (float*)d_out;
    unsigned short* xt = (unsigned short*)d_out;
    unsigned short* wt = (unsigned short*)(ws + WTOFF);

    prep_kernel<<<dim3(384), dim3(256), 0, stream>>>(x, wq, wk, wv, xt, wt);
    proj_gemm_kernel<<<dim3(144, 12), dim3(256), 0, stream>>>(xt, wt, ws);
    scores_partial_kernel<<<dim3(BB*HH*8), dim3(256), 0, stream>>>(relx, rely, ws);
    reduce_softmax_kernel<<<dim3(BB*HH), dim3(256), 0, stream>>>(ws);
    pv_kernel<<<dim3(BB*16*18), dim3(128), 0, stream>>>(bias, ws, out);
}